// Round 1
// baseline (268.418 us; speedup 1.0000x reference)
//
#include <hip/hip_runtime.h>
#include <hip/hip_bf16.h>

// Problem constants (fixed by reference)
#define B_    4
#define Qn_   2048
#define Ln_   4
#define Hn_   8
#define Pn_   4
#define Dn_   32
#define S_    21760   // 128*128 + 64*64 + 32*32 + 16*16

typedef short  short8  __attribute__((ext_vector_type(8)));
typedef float  floatx4 __attribute__((ext_vector_type(4)));

__device__ __forceinline__ unsigned short f2bf(float f) {
    unsigned int u = __builtin_bit_cast(unsigned int, f);
    u += 0x7fffu + ((u >> 16) & 1u);   // round-to-nearest-even
    return (unsigned short)(u >> 16);
}
__device__ __forceinline__ float bf2f(unsigned short h) {
    unsigned int u = ((unsigned int)h) << 16;
    return __builtin_bit_cast(float, u);
}

// ---------------------------------------------------------------------------
// Prep: W_val, W_out (256x256 f32, KxN) -> bf16 transposed (NxK)
// ---------------------------------------------------------------------------
__global__ void prep_w(const float* __restrict__ Wv, const float* __restrict__ Wo,
                       short* __restrict__ Wvt, short* __restrict__ Wot) {
    int k = blockIdx.x;     // 0..255 (row of W, coalesced read across threads)
    int n = threadIdx.x;    // 0..255
    Wvt[n * 256 + k] = (short)f2bf(Wv[k * 256 + n]);
    Wot[n * 256 + k] = (short)f2bf(Wo[k * 256 + n]);
}

// ---------------------------------------------------------------------------
// GEMM: C[M x 256] = A[M x 256] @ B[256 x 256] + bias
//   Bt: bf16, transposed (N x K) so B-fragments are contiguous 8*bf16.
//   4 waves/block, each wave: 16 rows x 256 cols, K-loop of 8 x 32.
//   mfma_f32_16x16x32_bf16: A row=lane&15, k=(lane>>4)*8+j (contiguous);
//                           B col=lane&15, same k; D col=lane&15, row=(lane>>4)*4+reg.
// ---------------------------------------------------------------------------
template<int A_BF16, int OUT_F32>
__global__ __launch_bounds__(256) void gemm256(const void* __restrict__ Av,
                                               const short* __restrict__ Bt,
                                               const float* __restrict__ bias,
                                               void* __restrict__ Cv) {
    const int lane = threadIdx.x & 63;
    const int wave = threadIdx.x >> 6;
    const int l16  = lane & 15;
    const int lq   = lane >> 4;
    const long row0 = (long)blockIdx.x * 64 + wave * 16;
    const long arow = row0 + l16;

    floatx4 acc[16];
#pragma unroll
    for (int i = 0; i < 16; ++i) acc[i] = (floatx4){0.f, 0.f, 0.f, 0.f};

    for (int kk = 0; kk < 8; ++kk) {
        const int k0 = kk * 32 + lq * 8;
        short8 a;
        if (A_BF16) {
            a = *(const short8*)((const short*)Av + arow * 256 + k0);
        } else {
            const float* ap = (const float*)Av + arow * 256 + k0;
            floatx4 f0 = *(const floatx4*)ap;
            floatx4 f1 = *(const floatx4*)(ap + 4);
#pragma unroll
            for (int j = 0; j < 4; ++j) {
                a[j]     = (short)f2bf(f0[j]);
                a[4 + j] = (short)f2bf(f1[j]);
            }
        }
#pragma unroll
        for (int nt = 0; nt < 16; ++nt) {
            short8 b = *(const short8*)(Bt + (nt * 16 + l16) * 256 + k0);
            acc[nt] = __builtin_amdgcn_mfma_f32_16x16x32_bf16(a, b, acc[nt], 0, 0, 0);
        }
    }

#pragma unroll
    for (int nt = 0; nt < 16; ++nt) {
        const int col = nt * 16 + l16;
        const float bv = bias[col];
#pragma unroll
        for (int r = 0; r < 4; ++r) {
            const long row = row0 + lq * 4 + r;
            const float v = acc[nt][r] + bv;
            if (OUT_F32) ((float*)Cv)[row * 256 + col] = v;
            else         ((short*)Cv)[row * 256 + col] = (short)f2bf(v);
        }
    }
}

// ---------------------------------------------------------------------------
// Fused per-query: off/attn GEMMs + softmax + deformable sampling -> wv (bf16)
// 512 threads, 16 queries per block. Grid = B * (Q/16) = 512.
// ---------------------------------------------------------------------------
__global__ __launch_bounds__(512) void fused_q(
        const float* __restrict__ in_feats, const float* __restrict__ priors,
        const int* __restrict__ shapes, const int* __restrict__ starts,
        const float* __restrict__ W_off, const float* __restrict__ b_off,
        const float* __restrict__ W_attn, const float* __restrict__ b_attn,
        const short* __restrict__ value, short* __restrict__ wv) {
    __shared__ float in_lds[16][256];
    __shared__ float off_lds[16][256];
    __shared__ float attn_lds[16][128];
    __shared__ float pri_lds[16][4][2];
    __shared__ int   shp_lds[4][2];
    __shared__ int   st_lds[4];

    const int tid = threadIdx.x;
    const int b   = blockIdx.x >> 7;
    const int qt  = blockIdx.x & 127;
    const long q0 = (long)qt * 16;

    // stage in_feats rows (16 x 256 f32), priors, shapes
    const float* src = in_feats + ((long)b * Qn_ + q0) * 256;
    for (int i = tid; i < 16 * 256 / 4; i += 512)
        ((floatx4*)in_lds)[i] = ((const floatx4*)src)[i];
    if (tid < 128) ((float*)pri_lds)[tid] = priors[((long)b * Qn_ + q0) * 8 + tid];
    if (tid < 8)  ((int*)shp_lds)[tid] = shapes[tid];
    if (tid < 4)  st_lds[tid] = starts[tid];
    __syncthreads();

    // off/attn GEMM: 16 queries x 384 outputs, 12 per thread
    for (int o = tid; o < 16 * 384; o += 512) {
        const int qi = o / 384;
        const int c  = o - qi * 384;
        float acc = 0.f;
        if (c < 256) {
            for (int k = 0; k < 256; ++k) acc += in_lds[qi][k] * W_off[k * 256 + c];
            off_lds[qi][c] = acc + b_off[c];
        } else {
            const int ca = c - 256;
            for (int k = 0; k < 256; ++k) acc += in_lds[qi][k] * W_attn[k * 128 + ca];
            attn_lds[qi][ca] = acc + b_attn[ca];
        }
    }
    __syncthreads();

    // softmax over L*P=16 per (q,h): 128 active threads
    if (tid < 128) {
        const int qi = tid >> 3, h = tid & 7;
        float* a = &attn_lds[qi][h * 16];
        float m = a[0];
        for (int i = 1; i < 16; ++i) m = fmaxf(m, a[i]);
        float s = 0.f;
        for (int i = 0; i < 16; ++i) { float e = expf(a[i] - m); a[i] = e; s += e; }
        const float inv = 1.f / s;
        for (int i = 0; i < 16; ++i) a[i] *= inv;
    }
    __syncthreads();

    // sampling: thread -> (qi, h, 8-channel slice)
    const int pairi = tid >> 2, sub = tid & 3;
    const int qi = pairi >> 3, h = pairi & 7;
    float acc[8];
#pragma unroll
    for (int j = 0; j < 8; ++j) acc[j] = 0.f;
    const short* vbase = value + (long)b * S_ * 256 + h * 32 + sub * 8;

    for (int l = 0; l < 4; ++l) {
        const int Hl = shp_lds[l][0], Wl = shp_lds[l][1];
        const int st = st_lds[l];
        const float px = pri_lds[qi][l][0], py = pri_lds[qi][l][1];
        const float invW = 1.f / (float)Wl, invH = 1.f / (float)Hl; // exact (pow2)
        for (int p = 0; p < 4; ++p) {
            const int cb = h * 16 + l * 4 + p;
            const float ox = off_lds[qi][cb * 2], oy = off_lds[qi][cb * 2 + 1];
            const float lx = px + ox * invW, ly = py + oy * invH;
            const float ix = lx * (float)Wl - 0.5f, iy = ly * (float)Hl - 0.5f;
            const float x0f = floorf(ix), y0f = floorf(iy);
            const int x0 = (int)x0f, y0 = (int)y0f;
            const float fx = ix - x0f, fy = iy - y0f;
            const float awv = attn_lds[qi][cb];
#pragma unroll
            for (int dy = 0; dy < 2; ++dy) {
                const int yc = y0 + dy;
                if (yc < 0 || yc >= Hl) continue;
                const float wy = dy ? fy : 1.f - fy;
#pragma unroll
                for (int dx = 0; dx < 2; ++dx) {
                    const int xc = x0 + dx;
                    if (xc < 0 || xc >= Wl) continue;
                    const float wx = dx ? fx : 1.f - fx;
                    const float w = wy * wx * awv;
                    const short8 v = *(const short8*)(vbase + ((long)st + (long)yc * Wl + xc) * 256);
#pragma unroll
                    for (int j = 0; j < 8; ++j) acc[j] += w * bf2f((unsigned short)v[j]);
                }
            }
        }
    }

    short8 ov;
#pragma unroll
    for (int j = 0; j < 8; ++j) ov[j] = (short)f2bf(acc[j]);
    *(short8*)(wv + (((long)b * Qn_ + q0 + qi) * 256 + h * 32 + sub * 8)) = ov;
}

// ---------------------------------------------------------------------------
extern "C" void kernel_launch(void* const* d_in, const int* in_sizes, int n_in,
                              void* d_out, int out_size, void* d_ws, size_t ws_size,
                              hipStream_t stream) {
    const float* in_feats = (const float*)d_in[0];
    const float* priors   = (const float*)d_in[1];
    const float* sfeats   = (const float*)d_in[2];
    const int*   shapes   = (const int*)d_in[3];
    const int*   starts   = (const int*)d_in[4];
    const float* W_off    = (const float*)d_in[5];
    const float* b_off    = (const float*)d_in[6];
    const float* W_attn   = (const float*)d_in[7];
    const float* b_attn   = (const float*)d_in[8];
    const float* W_val    = (const float*)d_in[9];
    const float* b_val    = (const float*)d_in[10];
    const float* W_out    = (const float*)d_in[11];
    const float* b_out    = (const float*)d_in[12];
    float* out = (float*)d_out;

    // Workspace layout (bytes): Wvt 128K | Wot 128K | value 44.56M | wv 4M  (~49 MB)
    short* Wvt   = (short*)d_ws;
    short* Wot   = Wvt + 65536;
    short* value = Wot + 65536;
    short* wv    = value + (long)B_ * S_ * 256;

    prep_w<<<256, 256, 0, stream>>>(W_val, W_out, Wvt, Wot);
    gemm256<0, 0><<<(B_ * S_) / 64, 256, 0, stream>>>((const void*)sfeats, Wvt, b_val, (void*)value);
    fused_q<<<B_ * (Qn_ / 16), 512, 0, stream>>>(in_feats, priors, shapes, starts,
                                                 W_off, b_off, W_attn, b_attn, value, wv);
    gemm256<1, 1><<<(B_ * Qn_) / 64, 256, 0, stream>>>((const void*)wv, Wot, b_out, (void*)out);
}

// Round 2
// 198.008 us; speedup vs baseline: 1.3556x; 1.3556x over previous
//
#include <hip/hip_runtime.h>
#include <hip/hip_bf16.h>

// Problem constants (fixed by reference)
#define B_    4
#define Qn_   2048
#define Ln_   4
#define Hn_   8
#define Pn_   4
#define Dn_   32
#define S_    21760   // 128*128 + 64*64 + 32*32 + 16*16

typedef short  short8  __attribute__((ext_vector_type(8)));
typedef float  floatx4 __attribute__((ext_vector_type(4)));

__device__ __forceinline__ unsigned short f2bf(float f) {
    unsigned int u = __builtin_bit_cast(unsigned int, f);
    u += 0x7fffu + ((u >> 16) & 1u);   // round-to-nearest-even
    return (unsigned short)(u >> 16);
}
__device__ __forceinline__ float bf2f(unsigned short h) {
    unsigned int u = ((unsigned int)h) << 16;
    return __builtin_bit_cast(float, u);
}

// ---------------------------------------------------------------------------
// Prep: cast+transpose weights to bf16 NxK, concat off|attn, concat biases.
//   grid 256 (= k), block 896.
// ---------------------------------------------------------------------------
__global__ __launch_bounds__(896) void prep_w(
        const float* __restrict__ Wv, const float* __restrict__ Wo,
        const float* __restrict__ Woff, const float* __restrict__ Wattn,
        const float* __restrict__ boff, const float* __restrict__ battn,
        short* __restrict__ Wvt, short* __restrict__ Wot,
        short* __restrict__ Wcat, float* __restrict__ bcat) {
    const int k = blockIdx.x;      // 0..255
    const int t = threadIdx.x;
    if (t < 256) {
        Wvt[t * 256 + k] = (short)f2bf(Wv[k * 256 + t]);
    } else if (t < 512) {
        const int n = t - 256;
        Wot[n * 256 + k] = (short)f2bf(Wo[k * 256 + n]);
    } else {
        const int n = t - 512;     // 0..383
        const float w = (n < 256) ? Woff[k * 256 + n] : Wattn[k * 128 + (n - 256)];
        Wcat[n * 256 + k] = (short)f2bf(w);
    }
    if (blockIdx.x == 0 && t < 384)
        bcat[t] = (t < 256) ? boff[t] : battn[t - 256];
}

// ---------------------------------------------------------------------------
// GEMM: C[M x NT*16] = A[M x 256] @ B[256 x NT*16] + bias
//   Bt: bf16 transposed (N x K) -> B-fragments are contiguous 8*bf16.
//   4 waves/block, wave = 16 rows x all N, K-loop 8 x 32.
// ---------------------------------------------------------------------------
template<int NT, int A_BF16, int OUT_F32>
__global__ __launch_bounds__(256) void gemm_mfma(const void* __restrict__ Av,
                                                 const short* __restrict__ Bt,
                                                 const float* __restrict__ bias,
                                                 void* __restrict__ Cv) {
    const int lane = threadIdx.x & 63;
    const int wave = threadIdx.x >> 6;
    const int l16  = lane & 15;
    const int lq   = lane >> 4;
    const long row0 = (long)blockIdx.x * 64 + wave * 16;
    const long arow = row0 + l16;
    const int  N    = NT * 16;

    floatx4 acc[NT];
#pragma unroll
    for (int i = 0; i < NT; ++i) acc[i] = (floatx4){0.f, 0.f, 0.f, 0.f};

    for (int kk = 0; kk < 8; ++kk) {
        const int k0 = kk * 32 + lq * 8;
        short8 a;
        if (A_BF16) {
            a = *(const short8*)((const short*)Av + arow * 256 + k0);
        } else {
            const float* ap = (const float*)Av + arow * 256 + k0;
            floatx4 f0 = *(const floatx4*)ap;
            floatx4 f1 = *(const floatx4*)(ap + 4);
#pragma unroll
            for (int j = 0; j < 4; ++j) {
                a[j]     = (short)f2bf(f0[j]);
                a[4 + j] = (short)f2bf(f1[j]);
            }
        }
#pragma unroll
        for (int nt = 0; nt < NT; ++nt) {
            short8 b = *(const short8*)(Bt + (nt * 16 + l16) * 256 + k0);
            acc[nt] = __builtin_amdgcn_mfma_f32_16x16x32_bf16(a, b, acc[nt], 0, 0, 0);
        }
    }

#pragma unroll
    for (int nt = 0; nt < NT; ++nt) {
        const int col = nt * 16 + l16;
        const float bv = bias[col];
#pragma unroll
        for (int r = 0; r < 4; ++r) {
            const long row = row0 + lq * 4 + r;
            const float v = acc[nt][r] + bv;
            if (OUT_F32) ((float*)Cv)[row * N + col] = v;
            else         ((short*)Cv)[row * N + col] = (short)f2bf(v);
        }
    }
}

// ---------------------------------------------------------------------------
// Sampler: softmax + deformable bilinear gather -> wv (bf16)
// 512 threads, 16 queries per block. Grid = B * (Q/16) = 512.
// ---------------------------------------------------------------------------
__global__ __launch_bounds__(512) void sampler(
        const float* __restrict__ priors,
        const int* __restrict__ shapes, const int* __restrict__ starts,
        const float* __restrict__ offattn,   // [B*Q][384]: 256 off | 128 attn logits
        const short* __restrict__ value, short* __restrict__ wv) {
    __shared__ float oa_lds[16][384];
    __shared__ float pri_lds[16][4][2];
    __shared__ int   shp_lds[4][2];
    __shared__ int   st_lds[4];

    const int tid = threadIdx.x;
    const int b   = blockIdx.x >> 7;
    const int qt  = blockIdx.x & 127;
    const long q0 = (long)qt * 16;

    const float* src = offattn + ((long)b * Qn_ + q0) * 384;
    for (int i = tid; i < 16 * 384 / 4; i += 512)
        ((floatx4*)oa_lds)[i] = ((const floatx4*)src)[i];
    if (tid < 128) ((float*)pri_lds)[tid] = priors[((long)b * Qn_ + q0) * 8 + tid];
    if (tid < 8)  ((int*)shp_lds)[tid] = shapes[tid];
    if (tid < 4)  st_lds[tid] = starts[tid];
    __syncthreads();

    // softmax over L*P=16 per (q,h): 128 active threads
    if (tid < 128) {
        const int qi = tid >> 3, h = tid & 7;
        float* a = &oa_lds[qi][256 + h * 16];
        float m = a[0];
        for (int i = 1; i < 16; ++i) m = fmaxf(m, a[i]);
        float s = 0.f;
        for (int i = 0; i < 16; ++i) { float e = expf(a[i] - m); a[i] = e; s += e; }
        const float inv = 1.f / s;
        for (int i = 0; i < 16; ++i) a[i] *= inv;
    }
    __syncthreads();

    // sampling: thread -> (qi, h, 8-channel slice); wave reads 512B segments
    const int pairi = tid >> 2, sub = tid & 3;
    const int qi = pairi >> 3, h = pairi & 7;
    float acc[8];
#pragma unroll
    for (int j = 0; j < 8; ++j) acc[j] = 0.f;
    const short* vbase = value + (long)b * S_ * 256 + h * 32 + sub * 8;

    for (int l = 0; l < 4; ++l) {
        const int Hl = shp_lds[l][0], Wl = shp_lds[l][1];
        const int st = st_lds[l];
        const float px = pri_lds[qi][l][0], py = pri_lds[qi][l][1];
        const float invW = 1.f / (float)Wl, invH = 1.f / (float)Hl; // exact (pow2)
        for (int p = 0; p < 4; ++p) {
            const int cb = h * 16 + l * 4 + p;
            const float ox = oa_lds[qi][cb * 2], oy = oa_lds[qi][cb * 2 + 1];
            const float lx = px + ox * invW, ly = py + oy * invH;
            const float ix = lx * (float)Wl - 0.5f, iy = ly * (float)Hl - 0.5f;
            const float x0f = floorf(ix), y0f = floorf(iy);
            const int x0 = (int)x0f, y0 = (int)y0f;
            const float fx = ix - x0f, fy = iy - y0f;
            const float awv = oa_lds[qi][256 + cb];
#pragma unroll
            for (int dy = 0; dy < 2; ++dy) {
                const int yc = y0 + dy;
                if (yc < 0 || yc >= Hl) continue;
                const float wy = dy ? fy : 1.f - fy;
#pragma unroll
                for (int dx = 0; dx < 2; ++dx) {
                    const int xc = x0 + dx;
                    if (xc < 0 || xc >= Wl) continue;
                    const float wx = dx ? fx : 1.f - fx;
                    const float w = wy * wx * awv;
                    const short8 v = *(const short8*)(vbase + ((long)st + (long)yc * Wl + xc) * 256);
#pragma unroll
                    for (int j = 0; j < 8; ++j) acc[j] += w * bf2f((unsigned short)v[j]);
                }
            }
        }
    }

    short8 ov;
#pragma unroll
    for (int j = 0; j < 8; ++j) ov[j] = (short)f2bf(acc[j]);
    *(short8*)(wv + (((long)b * Qn_ + q0 + qi) * 256 + h * 32 + sub * 8)) = ov;
}

// ---------------------------------------------------------------------------
extern "C" void kernel_launch(void* const* d_in, const int* in_sizes, int n_in,
                              void* d_out, int out_size, void* d_ws, size_t ws_size,
                              hipStream_t stream) {
    const float* in_feats = (const float*)d_in[0];
    const float* priors   = (const float*)d_in[1];
    const float* sfeats   = (const float*)d_in[2];
    const int*   shapes   = (const int*)d_in[3];
    const int*   starts   = (const int*)d_in[4];
    const float* W_off    = (const float*)d_in[5];
    const float* b_off    = (const float*)d_in[6];
    const float* W_attn   = (const float*)d_in[7];
    const float* b_attn   = (const float*)d_in[8];
    const float* W_val    = (const float*)d_in[9];
    const float* b_val    = (const float*)d_in[10];
    const float* W_out    = (const float*)d_in[11];
    const float* b_out    = (const float*)d_in[12];
    float* out = (float*)d_out;

    // Workspace layout:
    //   Wvt 128K | Wot 128K | Wcat 192K | value 44.56M | wv 4M   (bf16/short)
    //   offattn 12.58M | bcat 1.5K                               (f32)
    short* Wvt     = (short*)d_ws;
    short* Wot     = Wvt + 65536;
    short* Wcat    = Wot + 65536;
    short* value   = Wcat + 98304;
    short* wv      = value + (long)B_ * S_ * 256;
    float* offattn = (float*)(wv + (long)B_ * Qn_ * 256);
    float* bcat    = offattn + (long)B_ * Qn_ * 384;

    prep_w<<<256, 896, 0, stream>>>(W_val, W_out, W_off, W_attn, b_off, b_attn,
                                    Wvt, Wot, Wcat, bcat);
    // value = sample_feats @ W_val + b_val   (87040 x 256 x 256), bf16 out
    gemm_mfma<16, 0, 0><<<(B_ * S_) / 64, 256, 0, stream>>>(
        (const void*)sfeats, Wvt, b_val, (void*)value);
    // offattn = in_feats @ [W_off | W_attn] + bcat  (8192 x 384 x 256), f32 out
    gemm_mfma<24, 0, 1><<<(B_ * Qn_) / 64, 256, 0, stream>>>(
        (const void*)in_feats, Wcat, bcat, (void*)offattn);
    // softmax + deformable sampling
    sampler<<<B_ * (Qn_ / 16), 512, 0, stream>>>(priors, shapes, starts,
                                                 offattn, value, wv);
    // out = wv @ W_out + b_out   (8192 x 256 x 256), f32 out
    gemm_mfma<16, 1, 1><<<(B_ * Qn_) / 64, 256, 0, stream>>>(
        (const void*)wv, Wot, b_out, (void*)out);
}

// Round 4
// 100.582 us; speedup vs baseline: 2.6686x; 1.9686x over previous
//
#include <hip/hip_runtime.h>
#include <hip/hip_bf16.h>

// Problem constants (fixed by reference)
#define B_    4
#define Qn_   2048
#define S_    21760   // 128*128 + 64*64 + 32*32 + 16*16

typedef short  short8  __attribute__((ext_vector_type(8)));
typedef float  floatx4 __attribute__((ext_vector_type(4)));

__device__ __forceinline__ unsigned short f2bf(float f) {
    unsigned int u = __builtin_bit_cast(unsigned int, f);
    u += 0x7fffu + ((u >> 16) & 1u);   // round-to-nearest-even
    return (unsigned short)(u >> 16);
}
__device__ __forceinline__ float bf2f(unsigned short h) {
    unsigned int u = ((unsigned int)h) << 16;
    return __builtin_bit_cast(float, u);
}

// async global->LDS, 16B per lane. lds must be WAVE-UNIFORM base (lane*16 implicit).
__device__ __forceinline__ void async16(void* lds, const void* g) {
    __builtin_amdgcn_global_load_lds(
        (const __attribute__((address_space(1))) unsigned int*)g,
        (__attribute__((address_space(3))) unsigned int*)lds, 16, 0, 0);
}

// ---------------------------------------------------------------------------
// Prep: cast+transpose weights to bf16 NxK, concat off|attn, concat biases.
// ---------------------------------------------------------------------------
__global__ __launch_bounds__(896) void prep_w(
        const float* __restrict__ Wv, const float* __restrict__ Wo,
        const float* __restrict__ Woff, const float* __restrict__ Wattn,
        const float* __restrict__ boff, const float* __restrict__ battn,
        short* __restrict__ Wvt, short* __restrict__ Wot,
        short* __restrict__ Wcat, float* __restrict__ bcat) {
    const int k = blockIdx.x;      // 0..255
    const int t = threadIdx.x;
    if (t < 256) {
        Wvt[t * 256 + k] = (short)f2bf(Wv[k * 256 + t]);
    } else if (t < 512) {
        const int n = t - 256;
        Wot[n * 256 + k] = (short)f2bf(Wo[k * 256 + n]);
    } else {
        const int n = t - 512;     // 0..383
        const float w = (n < 256) ? Woff[k * 256 + n] : Wattn[k * 128 + (n - 256)];
        Wcat[n * 256 + k] = (short)f2bf(w);
    }
    if (blockIdx.x == 0 && t < 384)
        bcat[t] = (t < 256) ? boff[t] : battn[t - 256];
}

// ---------------------------------------------------------------------------
// Tiled GEMM: C[M x Ntot] = A[M x 256] @ B[256 x Ntot] + bias
//   Block: BM=128 rows x BN=NW*64 cols, NW*2 waves (wave = 64x64, 4x4 frags).
//   K-loop: 8 steps of BK=32, double-buffered LDS.
//   B (bf16 NxK "Bt") staged by global_load_lds; A f32 reg-staged w/ cvt,
//   A bf16 staged by global_load_lds (requires NW==4).
//   LDS tiles [rows][32] bf16 (64B rows); 16B-chunk XOR swizzle: chunk ^= row&3
//   applied on the GLOBAL source (linear LDS dest) and on ds_read addresses.
// ---------------------------------------------------------------------------
template<int NW, int A_BF16, int OUT_F32>
__global__ __launch_bounds__(NW * 128) void gemm_tile(
        const void* __restrict__ Av, const short* __restrict__ Bt,
        const float* __restrict__ bias, void* __restrict__ Cv, int Ntot) {
    constexpr int NT = NW * 128;
    constexpr int BN = NW * 64;
    constexpr int AIT = (512 + NT - 1) / NT;   // A f32 stage iters (512 chunks)
    __shared__ short As[2][128 * 32];
    __shared__ short Bs[2][BN * 32];

    const int tid  = threadIdx.x;
    const int lane = tid & 63, wave = tid >> 6;
    const int l16  = lane & 15, lq = lane >> 4;
    const int wr   = wave / NW, wc = wave % NW;
    const long row0 = (long)blockIdx.x * 128;
    const int  col0 = blockIdx.y * BN;

    floatx4 acc[4][4];
#pragma unroll
    for (int i = 0; i < 4; ++i)
#pragma unroll
        for (int j = 0; j < 4; ++j) acc[i][j] = (floatx4){0.f, 0.f, 0.f, 0.f};

    floatx4 a0[AIT], a1[AIT];

    // --- staging helpers ---
    auto loadA = [&](int kk) {            // f32 A -> regs
#pragma unroll
        for (int it = 0; it < AIT; ++it) {
            const int i = tid + it * NT;
            if (i < 512) {
                const int r = i >> 2, c = i & 3;
                const float* g = (const float*)Av + (row0 + r) * 256 + kk * 32 + c * 8;
                a0[it] = *(const floatx4*)g;
                a1[it] = *(const floatx4*)(g + 4);
            }
        }
    };
    auto writeA = [&](int bb) {           // regs -> cvt bf16 -> LDS (swizzled)
#pragma unroll
        for (int it = 0; it < AIT; ++it) {
            const int i = tid + it * NT;
            if (i < 512) {
                const int r = i >> 2, c = i & 3;
                short8 v;
#pragma unroll
                for (int j = 0; j < 4; ++j) {
                    v[j]     = (short)f2bf(a0[it][j]);
                    v[4 + j] = (short)f2bf(a1[it][j]);
                }
                *(short8*)&As[bb][r * 32 + ((c ^ (r & 3)) << 3)] = v;
            }
        }
    };
    auto stageA_lds = [&](int kk, int bb) {  // bf16 A via DMA (NT==512 only)
        const int r = tid >> 2, c = tid & 3;
        const short* g = (const short*)Av + (row0 + r) * 256 + kk * 32 + ((c ^ (r & 3)) << 3);
        async16(&As[bb][(wave << 6) * 8], g);
    };
    auto stageB = [&](int kk, int bb) {      // bf16 Bt via DMA, 2 calls
#pragma unroll
        for (int c2 = 0; c2 < 2; ++c2) {
            const int idx = c2 * NT + tid;
            const int r = idx >> 2, ch = idx & 3;
            const short* g = Bt + (long)(col0 + r) * 256 + kk * 32 + ((ch ^ (r & 3)) << 3);
            async16(&Bs[bb][(c2 * NT + (wave << 6)) * 8], g);
        }
    };

    // --- prologue ---
    if (!A_BF16) loadA(0);
    stageB(0, 0);
    if (A_BF16) stageA_lds(0, 0); else writeA(0);
    __syncthreads();

    // --- K loop ---
    int buf = 0;
    for (int kk = 0; kk < 8; ++kk) {
        const int nxt = buf ^ 1;
        if (kk < 7) {
            if (!A_BF16) loadA(kk + 1);
            stageB(kk + 1, nxt);
            if (A_BF16) stageA_lds(kk + 1, nxt);
        }
        short8 af[4], bv[4];
#pragma unroll
        for (int mf = 0; mf < 4; ++mf) {
            const int r = wr * 64 + mf * 16 + l16;
            af[mf] = *(const short8*)&As[buf][r * 32 + ((lq ^ (r & 3)) << 3)];
        }
#pragma unroll
        for (int nf = 0; nf < 4; ++nf) {
            const int r = wc * 64 + nf * 16 + l16;
            bv[nf] = *(const short8*)&Bs[buf][r * 32 + ((lq ^ (r & 3)) << 3)];
        }
#pragma unroll
        for (int mf = 0; mf < 4; ++mf)
#pragma unroll
            for (int nf = 0; nf < 4; ++nf)
                acc[mf][nf] = __builtin_amdgcn_mfma_f32_16x16x32_bf16(af[mf], bv[nf], acc[mf][nf], 0, 0, 0);
        if (!A_BF16 && kk < 7) writeA(nxt);
        __syncthreads();
        buf = nxt;
    }

    // --- epilogue: bias + store ---
#pragma unroll
    for (int nf = 0; nf < 4; ++nf) {
        const int col = col0 + wc * 64 + nf * 16 + l16;
        const float bvl = bias[col];
#pragma unroll
        for (int mf = 0; mf < 4; ++mf)
#pragma unroll
            for (int r = 0; r < 4; ++r) {
                const long row = row0 + wr * 64 + mf * 16 + lq * 4 + r;
                const float v = acc[mf][nf][r] + bvl;
                if (OUT_F32) ((float*)Cv)[row * Ntot + col] = v;
                else         ((short*)Cv)[row * Ntot + col] = (short)f2bf(v);
            }
    }
}

// ---------------------------------------------------------------------------
// Sampler: softmax + deformable bilinear gather -> wv (bf16)
// 512 threads, 16 queries per block. Grid = B * (Q/16) = 512.
// ---------------------------------------------------------------------------
__global__ __launch_bounds__(512) void sampler(
        const float* __restrict__ priors,
        const int* __restrict__ shapes, const int* __restrict__ starts,
        const float* __restrict__ offattn,   // [B*Q][384]: 256 off | 128 attn logits
        const short* __restrict__ value, short* __restrict__ wv) {
    __shared__ float oa_lds[16][384];
    __shared__ float pri_lds[16][4][2];
    __shared__ int   shp_lds[4][2];
    __shared__ int   st_lds[4];

    const int tid = threadIdx.x;
    const int b   = blockIdx.x >> 7;
    const int qt  = blockIdx.x & 127;
    const long q0 = (long)qt * 16;

    const float* src = offattn + ((long)b * Qn_ + q0) * 384;
    for (int i = tid; i < 16 * 384 / 4; i += 512)
        ((floatx4*)oa_lds)[i] = ((const floatx4*)src)[i];
    if (tid < 128) ((float*)pri_lds)[tid] = priors[((long)b * Qn_ + q0) * 8 + tid];
    if (tid < 8)  ((int*)shp_lds)[tid] = shapes[tid];
    if (tid < 4)  st_lds[tid] = starts[tid];
    __syncthreads();

    if (tid < 128) {
        const int qi = tid >> 3, h = tid & 7;
        float* a = &oa_lds[qi][256 + h * 16];
        float m = a[0];
        for (int i = 1; i < 16; ++i) m = fmaxf(m, a[i]);
        float s = 0.f;
        for (int i = 0; i < 16; ++i) { float e = expf(a[i] - m); a[i] = e; s += e; }
        const float inv = 1.f / s;
        for (int i = 0; i < 16; ++i) a[i] *= inv;
    }
    __syncthreads();

    const int pairi = tid >> 2, sub = tid & 3;
    const int qi = pairi >> 3, h = pairi & 7;
    float acc[8];
#pragma unroll
    for (int j = 0; j < 8; ++j) acc[j] = 0.f;
    const short* vbase = value + (long)b * S_ * 256 + h * 32 + sub * 8;

    for (int l = 0; l < 4; ++l) {
        const int Hl = shp_lds[l][0], Wl = shp_lds[l][1];
        const int st = st_lds[l];
        const float px = pri_lds[qi][l][0], py = pri_lds[qi][l][1];
        const float invW = 1.f / (float)Wl, invH = 1.f / (float)Hl;
        for (int p = 0; p < 4; ++p) {
            const int cb = h * 16 + l * 4 + p;
            const float ox = oa_lds[qi][cb * 2], oy = oa_lds[qi][cb * 2 + 1];
            const float lx = px + ox * invW, ly = py + oy * invH;
            const float ix = lx * (float)Wl - 0.5f, iy = ly * (float)Hl - 0.5f;
            const float x0f = floorf(ix), y0f = floorf(iy);
            const int x0 = (int)x0f, y0 = (int)y0f;
            const float fx = ix - x0f, fy = iy - y0f;
            const float awv = oa_lds[qi][256 + cb];
#pragma unroll
            for (int dy = 0; dy < 2; ++dy) {
                const int yc = y0 + dy;
                if (yc < 0 || yc >= Hl) continue;
                const float wy = dy ? fy : 1.f - fy;
#pragma unroll
                for (int dx = 0; dx < 2; ++dx) {
                    const int xc = x0 + dx;
                    if (xc < 0 || xc >= Wl) continue;
                    const float wx = dx ? fx : 1.f - fx;
                    const float w = wy * wx * awv;
                    const short8 v = *(const short8*)(vbase + ((long)st + (long)yc * Wl + xc) * 256);
#pragma unroll
                    for (int j = 0; j < 8; ++j) acc[j] += w * bf2f((unsigned short)v[j]);
                }
            }
        }
    }

    short8 ov;
#pragma unroll
    for (int j = 0; j < 8; ++j) ov[j] = (short)f2bf(acc[j]);
    *(short8*)(wv + (((long)b * Qn_ + q0 + qi) * 256 + h * 32 + sub * 8)) = ov;
}

// ---------------------------------------------------------------------------
extern "C" void kernel_launch(void* const* d_in, const int* in_sizes, int n_in,
                              void* d_out, int out_size, void* d_ws, size_t ws_size,
                              hipStream_t stream) {
    const float* in_feats = (const float*)d_in[0];
    const float* priors   = (const float*)d_in[1];
    const float* sfeats   = (const float*)d_in[2];
    const int*   shapes   = (const int*)d_in[3];
    const int*   starts   = (const int*)d_in[4];
    const float* W_off    = (const float*)d_in[5];
    const float* b_off    = (const float*)d_in[6];
    const float* W_attn   = (const float*)d_in[7];
    const float* b_attn   = (const float*)d_in[8];
    const float* W_val    = (const float*)d_in[9];
    const float* b_val    = (const float*)d_in[10];
    const float* W_out    = (const float*)d_in[11];
    const float* b_out    = (const float*)d_in[12];
    float* out = (float*)d_out;

    // Workspace: Wvt 128K | Wot 128K | Wcat 192K | value 44.56M | wv 4M (short)
    //            offattn 12.58M | bcat 1.5K (f32)
    short* Wvt     = (short*)d_ws;
    short* Wot     = Wvt + 65536;
    short* Wcat    = Wot + 65536;
    short* value   = Wcat + 98304;
    short* wv      = value + (long)B_ * S_ * 256;
    float* offattn = (float*)(wv + (long)B_ * Qn_ * 256);
    float* bcat    = offattn + (long)B_ * Qn_ * 384;

    prep_w<<<256, 896, 0, stream>>>(W_val, W_out, W_off, W_attn, b_off, b_attn,
                                    Wvt, Wot, Wcat, bcat);
    // value = sample_feats @ W_val + b_val   (87040 x 256), bf16 out
    gemm_tile<4, 0, 0><<<dim3((B_ * S_) / 128, 1), 512, 0, stream>>>(
        (const void*)sfeats, Wvt, b_val, (void*)value, 256);
    // offattn = in_feats @ [W_off|W_attn] + bcat  (8192 x 384), f32 out
    gemm_tile<3, 0, 1><<<dim3((B_ * Qn_) / 128, 2), 384, 0, stream>>>(
        (const void*)in_feats, Wcat, bcat, (void*)offattn, 384);
    // softmax + deformable sampling
    sampler<<<B_ * (Qn_ / 16), 512, 0, stream>>>(priors, shapes, starts,
                                                 offattn, value, wv);
    // out = wv @ W_out + b_out   (8192 x 256), f32 out
    gemm_tile<4, 1, 1><<<dim3((B_ * Qn_) / 128, 1), 512, 0, stream>>>(
        (const void*)wv, Wot, b_out, (void*)out, 256);
}